// Round 14
// baseline (196.479 us; speedup 1.0000x reference)
//
#include <hip/hip_runtime.h>
#include <hip/hip_bf16.h>
#include <hip/hip_cooperative_groups.h>

namespace cg = cooperative_groups;

#define N_NODES 500000
#define N_FEAT 125
#define HID 128
#define OUTD 64
#define N_GRAPHS 4096
#define N_TYPES 100
#define NPAIRS 7813   /* ceil(500000/64); pairs 0..7811 = 64 nodes, pair 7812 = 32 nodes */
#define NBLOCKS 256   /* 1 block/CU; co-resident -> cooperative grid.sync is safe */
#define NWAVES 8
#define WPAD 136      /* bf16 row stride: 16B-aligned; 68 dwords == 4 mod 32 banks */

typedef float f32x4 __attribute__((ext_vector_type(4)));
typedef short s16x8 __attribute__((ext_vector_type(8)));
typedef short s16x4 __attribute__((ext_vector_type(4)));

// LDS layout (bytes) — T + W2 + W3(K16 A-frags) + bias + W1 pos rows (R10).
#define OFF_T 0
#define SZ_T (N_TYPES * WPAD * 2)                  // 27200
#define OFF_W2 (OFF_T + SZ_T)                      // 27200
#define OFF_W3K (OFF_W2 + HID * WPAD * 2)          // 62016 (4 ob x 8 oi x 64 lanes x 8B)
#define OFF_B2 (OFF_W3K + 4 * 8 * 64 * 8)          // 78400
#define OFF_W1 (OFF_B2 + HID * 4)                  // 78912 (W1 pos rows, f32 3x128)
#define LDS_BYTES (OFF_W1 + 3 * HID * 4)           // 80448

// ws layout (bytes)
#define WS_GSUM 0
#define WS_GCNT ((size_t)N_GRAPHS * OUTD * 4)      // 1048576
#define WS_T    (WS_GCNT + (size_t)N_GRAPHS * 4)   // 1064960
#define WS_ZERO WS_T                               // bytes zeroed (gsum+gcnt)
#define WS_ZERO_V4 (WS_ZERO / 16)                  // 66560 f32x4

__device__ __forceinline__ unsigned short f2bf(float f) {
  union { float f; unsigned u; } v; v.f = f;
  unsigned r = v.u + 0x7FFFu + ((v.u >> 16) & 1u);  // RNE
  return (unsigned short)(r >> 16);
}
__device__ __forceinline__ float bf2f(unsigned short u) {
  union { unsigned u; float f; } v; v.u = ((unsigned)u) << 16;
  return v.f;
}
__device__ __forceinline__ unsigned pk2bf(float a, float b) {
  __hip_bfloat162 h = __float22bfloat162_rn(float2{a, b});   // .x -> low 16, .y -> high 16
  union { __hip_bfloat162 h; unsigned u; } v; v.h = h;
  return v.u;
}
__device__ __forceinline__ s16x4 u2frag(uint2 v) {
  union { uint2 u; s16x4 s; } c; c.u = v; return c.s;
}

// ---- ONE cooperative kernel: zero+prep -> grid.sync -> main -> grid.sync ->
// finalize.  Removes 2 dispatch boundaries (~75us of total was outside main
// across R1-R13).  256 blocks x 512 thr at 1 block/CU = co-resident.
extern "C" __global__ void __launch_bounds__(512, 2)
gnn_all(const float* __restrict__ pos, const int* __restrict__ z,
        const int* __restrict__ batch, const float* __restrict__ emb,
        const float* __restrict__ W1, const float* __restrict__ b1,
        const float* __restrict__ W2, const float* __restrict__ b2,
        const float* __restrict__ W3, const float* __restrict__ b3,
        float* __restrict__ gsum, int* __restrict__ gcnt,
        unsigned short* __restrict__ Tg, float* __restrict__ out)
{
  extern __shared__ char lds[];
  unsigned short* Tl  = (unsigned short*)(lds + OFF_T);
  unsigned short* w2t = (unsigned short*)(lds + OFF_W2);
  uint2* w3k = (uint2*)(lds + OFF_W3K);
  float* bias2 = (float*)(lds + OFF_B2);
  float* w1l   = (float*)(lds + OFF_W1);

  const int t = threadIdx.x, bid = blockIdx.x;

  // ---- phase 0: zero gsum/gcnt (all blocks) + T-table (blocks 0..99) ----
  {
    f32x4* wsz = (f32x4*)gsum;                     // gsum is the ws base
    for (int i = bid * 512 + t; i < WS_ZERO_V4; i += NBLOCKS * 512)
      wsz[i] = (f32x4){0.f, 0.f, 0.f, 0.f};
    if (bid < N_TYPES && t < HID) {                // T[100][128] = emb@W1[3:,:]+b1
      float acc = b1[t];
      const float* er = emb + bid * N_FEAT;
      for (int k = 0; k < N_FEAT; ++k)
        acc = fmaf(er[k], W1[(3 + k) * HID + t], acc);
      Tg[bid * HID + t] = f2bf(acc);
    }
  }

  // ---- stage weight tables (independent of phase 0 outputs) ----
  for (int i = t; i < HID * HID; i += 512) {       // W2^T [n][k] bf16
    int k = i >> 7, n = i & 127;
    w2t[n * WPAD + k] = f2bf(W2[i]);
  }
  // W3 as per-lane K=16 A-fragments: idx = (ob*8+oi)*64 + lane.
  for (int i = t; i < 4 * 8 * 64; i += 512) {
    int ob = i >> 9, rest = i & 511;
    int oi = rest >> 6, ln = rest & 63;
    int q = ln >> 4, l = ln & 15;
    int f0 = oi * 16 + q * 4, o = ob * 16 + l;
    uint2 v;
    v.x = pk2bf(W3[(f0 + 0) * OUTD + o], W3[(f0 + 1) * OUTD + o]);
    v.y = pk2bf(W3[(f0 + 2) * OUTD + o], W3[(f0 + 3) * OUTD + o]);
    w3k[i] = v;
  }
  if (t < HID) bias2[t] = b2[t];
  if (t < 3 * HID) w1l[t] = W1[t];                 // pos rows of W1, f32

  cg::this_grid().sync();                          // T visible device-wide

  // ---- stage T (written by other blocks) ----
  for (int i = t; i < N_TYPES * HID; i += 512) {   // T: bf16, padded rows
    int g = i >> 7, f = i & 127;
    Tl[g * WPAD + f] = Tg[i];
  }

  const int wave = t >> 6, lane = t & 63, quad = lane >> 4, l15 = lane & 15;

  __syncthreads();

  // ================= main loop: exact R10 body (57.1us, session best) =======
  const int gwave = bid * NWAVES + wave;

  for (int pair = gwave; pair < NPAIRS; pair += NBLOCKS * NWAVES) {
    const int base = pair * 64;
    const bool has2 = (pair != NPAIRS - 1);        // last pair: only 32 real nodes

    int id0 = batch[base + l15];
    int id1 = batch[base + 16 + l15];
    int id2 = -1, id3 = -1;
    if (has2) {
      id2 = batch[base + 32 + l15];
      id3 = batch[base + 48 + l15];
    }

    // ---- layer 1 in VALU, directly into MFMA B-fragments (x^T operand) ----
    s16x8 a[4][4];
    {
      float px[4], py[4], pz[4];
      const unsigned short* Tr[4];
      #pragma unroll
      for (int m = 0; m < 4; ++m) {
        int node = base + m * 16 + l15;
        node = node < N_NODES ? node : N_NODES - 1;   // clamp fake half of last pair
        const int zi = z[node];
        px[m] = pos[node * 3]; py[m] = pos[node * 3 + 1]; pz[m] = pos[node * 3 + 2];
        Tr[m] = Tl + zi * WPAD;
      }
      #pragma unroll
      for (int k = 0; k < 4; ++k) {
        float w1s[3][8];                           // broadcast within quads
        #pragma unroll
        for (int c = 0; c < 3; ++c) {
          *(f32x4*)&w1s[c][0] = *(const f32x4*)(w1l + c * HID + k * 32 + quad * 8);
          *(f32x4*)&w1s[c][4] = *(const f32x4*)(w1l + c * HID + k * 32 + quad * 8 + 4);
        }
        #pragma unroll
        for (int m = 0; m < 4; ++m) {
          s16x8 tf = *(const s16x8*)(Tr[m] + k * 32 + quad * 8);
          s16x8 fr;
          #pragma unroll
          for (int j = 0; j < 8; j += 2) {
            float v0 = bf2f((unsigned short)tf[j])
                     + px[m] * w1s[0][j] + py[m] * w1s[1][j] + pz[m] * w1s[2][j];
            float v1 = bf2f((unsigned short)tf[j + 1])
                     + px[m] * w1s[0][j + 1] + py[m] * w1s[1][j + 1] + pz[m] * w1s[2][j + 1];
            ((unsigned*)&fr)[j >> 1] = pk2bf(fmaxf(v0, 0.f), fmaxf(v1, 0.f));
          }
          a[m][k] = fr;
        }
      }
    }

    // ---- layer 2 + fused epilogue: the packed C-strip IS a K=16 B-fragment ----
    uint2 pb[8][4];
    __builtin_amdgcn_s_setprio(1);
    #pragma unroll
    for (int oi = 0; oi < 8; ++oi) {
      f32x4 c[4] = {};
      #pragma unroll
      for (int k = 0; k < 4; ++k) {
        s16x8 w = *(const s16x8*)(w2t + (oi * 16 + l15) * WPAD + k * 32 + quad * 8);
        #pragma unroll
        for (int m = 0; m < 4; ++m)
          c[m] = __builtin_amdgcn_mfma_f32_16x16x32_bf16(w, a[m][k], c[m], 0, 0, 0);
      }
      const int f0 = oi * 16 + quad * 4;
      f32x4 bv = *(const f32x4*)(bias2 + f0);
      #pragma unroll
      for (int m = 0; m < 4; ++m) {
        pb[oi][m].x = pk2bf(fmaxf(c[m][0] + bv[0], 0.f), fmaxf(c[m][1] + bv[1], 0.f));
        pb[oi][m].y = pk2bf(fmaxf(c[m][2] + bv[2], 0.f), fmaxf(c[m][3] + bv[3], 0.f));
      }
    }
    __builtin_amdgcn_s_setprio(0);

    // ---- layer 3: mfma_f32_16x16x16_bf16, K-block = oi strip ----
    f32x4 acc3[4][4] = {};
    __builtin_amdgcn_s_setprio(1);
    #pragma unroll
    for (int ob = 0; ob < 4; ++ob)
      #pragma unroll
      for (int oi = 0; oi < 8; ++oi) {
        s16x4 wa = u2frag(w3k[(ob * 8 + oi) * 64 + lane]);
        #pragma unroll
        for (int m = 0; m < 4; ++m)
          acc3[ob][m] = __builtin_amdgcn_mfma_f32_16x16x16bf16_1k(
              wa, u2frag(pb[oi][m]), acc3[ob][m], 0, 0, 0);
      }
    __builtin_amdgcn_s_setprio(0);

    // ---- pool: in-register segmented reduce over up to 64 sorted columns ----
    {
      const int NT = has2 ? 64 : 32;
      int done = 0;
      while (done < NT) {                          // wave-uniform loop
        const int sel = done >> 4;
        int srcv = (sel & 2) ? ((sel & 1) ? id3 : id2)
                             : ((sel & 1) ? id1 : id0);
        const int g = __builtin_amdgcn_readlane(srcv, done & 15);
        const bool m0 = (id0 == g), m1 = (id1 == g), m2 = (id2 == g), m3 = (id3 == g);
        float red[4][4];
        #pragma unroll
        for (int ob = 0; ob < 4; ++ob)
          #pragma unroll
          for (int r = 0; r < 4; ++r)
            red[ob][r] = (m0 ? acc3[ob][0][r] : 0.f) + (m1 ? acc3[ob][1][r] : 0.f)
                       + (m2 ? acc3[ob][2][r] : 0.f) + (m3 ? acc3[ob][3][r] : 0.f);
        #pragma unroll
        for (int s = 1; s <= 8; s <<= 1)
          #pragma unroll
          for (int ob = 0; ob < 4; ++ob)
            #pragma unroll
            for (int r = 0; r < 4; ++r)
              red[ob][r] += __shfl_xor(red[ob][r], s, 64);
        const int cnt = (int)((__popcll(__ballot(m0)) + __popcll(__ballot(m1)) +
                               __popcll(__ballot(m2)) + __popcll(__ballot(m3))) >> 2);
        if (l15 == 0) {                            // 4 lanes (one per quad) fire atomics
          #pragma unroll
          for (int ob = 0; ob < 4; ++ob)
            #pragma unroll
            for (int r = 0; r < 4; ++r)
              atomicAdd(&gsum[g * OUTD + ob * 16 + quad * 4 + r], red[ob][r]);
        }
        if (lane == 0) atomicAdd(&gcnt[g], cnt);
        done += cnt;                               // cnt >= 1: column `done` matches g
      }
    }
  }
  // ================= end main loop ==========================================

  cg::this_grid().sync();                          // all atomics device-visible

  // ---- finalize, spread over all blocks (2 elements/thread) ----
  for (int i = bid * 512 + t; i < N_GRAPHS * OUTD; i += NBLOCKS * 512) {
    int g = i >> 6, o = i & 63;
    int c = gcnt[g];
    out[i] = (c > 0) ? (gsum[i] / (float)c + b3[o]) : 0.f;
  }
}

extern "C" void kernel_launch(void* const* d_in, const int* in_sizes, int n_in,
                              void* d_out, int out_size, void* d_ws, size_t ws_size,
                              hipStream_t stream) {
  const float* pos  = (const float*)d_in[0];
  const int*   z    = (const int*)d_in[1];
  const int*   batch= (const int*)d_in[2];
  const float* emb  = (const float*)d_in[3];
  const float* W1   = (const float*)d_in[4];
  const float* b1   = (const float*)d_in[5];
  const float* W2   = (const float*)d_in[6];
  const float* b2   = (const float*)d_in[7];
  const float* W3   = (const float*)d_in[8];
  const float* b3   = (const float*)d_in[9];

  float* gsum = (float*)d_ws;
  int*   gcnt = (int*)((char*)d_ws + WS_GCNT);
  unsigned short* Tg = (unsigned short*)((char*)d_ws + WS_T);
  float* outp = (float*)d_out;

  hipFuncSetAttribute((const void*)gnn_all,
                      hipFuncAttributeMaxDynamicSharedMemorySize, LDS_BYTES);

  void* args[] = {(void*)&pos, (void*)&z, (void*)&batch, (void*)&emb,
                  (void*)&W1, (void*)&b1, (void*)&W2, (void*)&b2,
                  (void*)&W3, (void*)&b3,
                  (void*)&gsum, (void*)&gcnt, (void*)&Tg, (void*)&outp};
  hipLaunchCooperativeKernel((const void*)gnn_all, dim3(NBLOCKS), dim3(512),
                             args, LDS_BYTES, stream);
}

// Round 15
// 132.465 us; speedup vs baseline: 1.4832x; 1.4832x over previous
//
#include <hip/hip_runtime.h>
#include <hip/hip_bf16.h>

#define N_NODES 500000
#define N_FEAT 125
#define HID 128
#define OUTD 64
#define N_GRAPHS 4096
#define N_TYPES 100
#define NPAIRS 7813   /* ceil(500000/64); pairs 0..7811 = 64 nodes, pair 7812 = 32 nodes */
#define NBLOCKS 256   /* 1 block/CU; occupancy reg-capped at 2 waves/SIMD (R2-R9) */
#define NWAVES 8
#define WPAD 136      /* bf16 row stride: 16B-aligned; 68 dwords == 4 mod 32 banks */

typedef float f32x4 __attribute__((ext_vector_type(4)));
typedef short s16x8 __attribute__((ext_vector_type(8)));
typedef short s16x4 __attribute__((ext_vector_type(4)));

// LDS layout (bytes) — T + W2 + W3(K16 A-frags) + bias + W1 pos rows.
#define OFF_T 0
#define SZ_T (N_TYPES * WPAD * 2)                  // 27200
#define OFF_W2 (OFF_T + SZ_T)                      // 27200
#define OFF_W3K (OFF_W2 + HID * WPAD * 2)          // 62016 (4 ob x 8 oi x 64 lanes x 8B)
#define OFF_B2 (OFF_W3K + 4 * 8 * 64 * 8)          // 78400
#define OFF_W1 (OFF_B2 + HID * 4)                  // 78912 (W1 pos rows, f32 3x128)
#define LDS_BYTES (OFF_W1 + 3 * HID * 4)           // 80448

// ws layout (bytes)
#define WS_GSUM 0
#define WS_GCNT ((size_t)N_GRAPHS * OUTD * 4)      // 1048576
#define WS_T    (WS_GCNT + (size_t)N_GRAPHS * 4)   // 1064960
#define WS_ZERO WS_T                               // bytes zeroed (gsum+gcnt)
#define WS_ZERO_V4 (WS_ZERO / 16)                  // 66560 f32x4

__device__ __forceinline__ unsigned short f2bf(float f) {
  union { float f; unsigned u; } v; v.f = f;
  unsigned r = v.u + 0x7FFFu + ((v.u >> 16) & 1u);  // RNE
  return (unsigned short)(r >> 16);
}
__device__ __forceinline__ float bf2f(unsigned short u) {
  union { unsigned u; float f; } v; v.u = ((unsigned)u) << 16;
  return v.f;
}
__device__ __forceinline__ unsigned pk2bf(float a, float b) {
  __hip_bfloat162 h = __float22bfloat162_rn(float2{a, b});   // .x -> low 16, .y -> high 16
  union { __hip_bfloat162 h; unsigned u; } v; v.h = h;
  return v.u;
}
__device__ __forceinline__ s16x4 u2frag(uint2 v) {
  union { uint2 u; s16x4 s; } c; c.u = v; return c.s;
}

// ---- pre-pass: T[100][128] = emb @ W1[3:,:] + b1 (fp32 math, bf16 store) ----
extern "C" __global__ void gnn_prep(const float* __restrict__ emb,
                                    const float* __restrict__ W1,
                                    const float* __restrict__ b1,
                                    unsigned short* __restrict__ Tg,
                                    f32x4* __restrict__ wsz)
{
  const int j = threadIdx.x;                       // 256 blocks x 128 threads
  const int tid = blockIdx.x * 128 + j;
  for (int i = tid; i < WS_ZERO_V4; i += 256 * 128)
    wsz[i] = (f32x4){0.f, 0.f, 0.f, 0.f};
  const int g = blockIdx.x;
  if (g < N_TYPES) {
    float acc = b1[j];
    const float* er = emb + g * N_FEAT;
    for (int k = 0; k < N_FEAT; ++k)
      acc = fmaf(er[k], W1[(3 + k) * HID + j], acc);   // W1 read coalesced over j
    Tg[g * HID + j] = f2bf(acc);
  }
}

extern "C" __global__ void __launch_bounds__(512, 2)
gnn_main(const float* __restrict__ pos, const int* __restrict__ z,
         const int* __restrict__ batch, const unsigned short* __restrict__ Tg,
         const float* __restrict__ W1, const float* __restrict__ W2,
         const float* __restrict__ b2, const float* __restrict__ W3,
         float* __restrict__ gsum, int* __restrict__ gcnt)
{
  extern __shared__ char lds[];
  unsigned short* Tl  = (unsigned short*)(lds + OFF_T);
  unsigned short* w2t = (unsigned short*)(lds + OFF_W2);
  uint2* w3k = (uint2*)(lds + OFF_W3K);
  float* bias2 = (float*)(lds + OFF_B2);
  float* w1l   = (float*)(lds + OFF_W1);

  const int t = threadIdx.x;

  // ---- stage once per block ----
  for (int i = t; i < N_TYPES * HID; i += 512) {   // T: bf16, padded rows
    int g = i >> 7, f = i & 127;
    Tl[g * WPAD + f] = Tg[i];
  }
  for (int i = t; i < HID * HID; i += 512) {       // W2^T [n][k] bf16
    int k = i >> 7, n = i & 127;
    w2t[n * WPAD + k] = f2bf(W2[i]);
  }
  // W3 as per-lane K=16 A-fragments: idx = (ob*8+oi)*64 + lane.
  for (int i = t; i < 4 * 8 * 64; i += 512) {
    int ob = i >> 9, rest = i & 511;
    int oi = rest >> 6, ln = rest & 63;
    int q = ln >> 4, l = ln & 15;
    int f0 = oi * 16 + q * 4, o = ob * 16 + l;
    uint2 v;
    v.x = pk2bf(W3[(f0 + 0) * OUTD + o], W3[(f0 + 1) * OUTD + o]);
    v.y = pk2bf(W3[(f0 + 2) * OUTD + o], W3[(f0 + 3) * OUTD + o]);
    w3k[i] = v;
  }
  if (t < HID) bias2[t] = b2[t];
  if (t < 3 * HID) w1l[t] = W1[t];                 // pos rows of W1, f32

  const int wave = t >> 6, lane = t & 63, quad = lane >> 4, l15 = lane & 15;

  __syncthreads();   // the ONLY block-wide barrier

  const int gwave = blockIdx.x * NWAVES + wave;

  // 64 nodes (2 tiles) per iteration: W2/W3/bias/w1 LDS reads amortize over 2x
  // nodes (DS pipe was the R7 limiter at 2 waves/SIMD), and each MFMA stage has
  // 4 independent accumulator chains (2x ILP).  Occupancy stays 2 waves/SIMD by
  // design — the (512,4)/128-reg path spills unconditionally (R2/R3/R5/R9).
  for (int pair = gwave; pair < NPAIRS; pair += NBLOCKS * NWAVES) {
    const int base = pair * 64;
    const bool has2 = (pair != NPAIRS - 1);        // last pair: only 32 real nodes

    int id0 = batch[base + l15];
    int id1 = batch[base + 16 + l15];
    int id2 = -1, id3 = -1;
    if (has2) {
      id2 = batch[base + 32 + l15];
      id3 = batch[base + 48 + l15];
    }

    // ---- layer 1 in VALU, directly into MFMA B-fragments (x^T operand) ----
    // h1[node][f] = relu(T[z][f] + px*W1r0[f] + py*W1r1[f] + pz*W1r2[f])
    s16x8 a[4][4];
    {
      float px[4], py[4], pz[4];
      const unsigned short* Tr[4];
      #pragma unroll
      for (int m = 0; m < 4; ++m) {
        int node = base + m * 16 + l15;
        node = node < N_NODES ? node : N_NODES - 1;   // clamp fake half of last pair
        const int zi = z[node];
        px[m] = pos[node * 3]; py[m] = pos[node * 3 + 1]; pz[m] = pos[node * 3 + 2];
        Tr[m] = Tl + zi * WPAD;
      }
      #pragma unroll
      for (int k = 0; k < 4; ++k) {
        float w1s[3][8];                           // broadcast within quads
        #pragma unroll
        for (int c = 0; c < 3; ++c) {
          *(f32x4*)&w1s[c][0] = *(const f32x4*)(w1l + c * HID + k * 32 + quad * 8);
          *(f32x4*)&w1s[c][4] = *(const f32x4*)(w1l + c * HID + k * 32 + quad * 8 + 4);
        }
        #pragma unroll
        for (int m = 0; m < 4; ++m) {
          s16x8 tf = *(const s16x8*)(Tr[m] + k * 32 + quad * 8);
          s16x8 fr;
          #pragma unroll
          for (int j = 0; j < 8; j += 2) {
            float v0 = bf2f((unsigned short)tf[j])
                     + px[m] * w1s[0][j] + py[m] * w1s[1][j] + pz[m] * w1s[2][j];
            float v1 = bf2f((unsigned short)tf[j + 1])
                     + px[m] * w1s[0][j + 1] + py[m] * w1s[1][j + 1] + pz[m] * w1s[2][j + 1];
            ((unsigned*)&fr)[j >> 1] = pk2bf(fmaxf(v0, 0.f), fmaxf(v1, 0.f));
          }
          a[m][k] = fr;
        }
      }
    }

    // ---- layer 2 + fused epilogue: the packed C-strip IS a K=16 B-fragment ----
    // Each w2t fragment load now feeds 4 MFMAs (was 2).
    uint2 pb[8][4];
    __builtin_amdgcn_s_setprio(1);
    #pragma unroll
    for (int oi = 0; oi < 8; ++oi) {
      f32x4 c[4] = {};
      #pragma unroll
      for (int k = 0; k < 4; ++k) {
        s16x8 w = *(const s16x8*)(w2t + (oi * 16 + l15) * WPAD + k * 32 + quad * 8);
        #pragma unroll
        for (int m = 0; m < 4; ++m)
          c[m] = __builtin_amdgcn_mfma_f32_16x16x32_bf16(w, a[m][k], c[m], 0, 0, 0);
      }
      const int f0 = oi * 16 + quad * 4;
      f32x4 bv = *(const f32x4*)(bias2 + f0);
      #pragma unroll
      for (int m = 0; m < 4; ++m) {
        pb[oi][m].x = pk2bf(fmaxf(c[m][0] + bv[0], 0.f), fmaxf(c[m][1] + bv[1], 0.f));
        pb[oi][m].y = pk2bf(fmaxf(c[m][2] + bv[2], 0.f), fmaxf(c[m][3] + bv[3], 0.f));
      }
    }
    __builtin_amdgcn_s_setprio(0);

    // ---- layer 3: mfma_f32_16x16x16_bf16, K-block = oi strip; wa feeds 4 MFMAs
    f32x4 acc3[4][4] = {};
    __builtin_amdgcn_s_setprio(1);
    #pragma unroll
    for (int ob = 0; ob < 4; ++ob)
      #pragma unroll
      for (int oi = 0; oi < 8; ++oi) {
        s16x4 wa = u2frag(w3k[(ob * 8 + oi) * 64 + lane]);
        #pragma unroll
        for (int m = 0; m < 4; ++m)
          acc3[ob][m] = __builtin_amdgcn_mfma_f32_16x16x16bf16_1k(
              wa, u2frag(pb[oi][m]), acc3[ob][m], 0, 0, 0);
      }
    __builtin_amdgcn_s_setprio(0);

    // ---- pool: in-register segmented reduce over up to 64 sorted columns ----
    // acc3[ob][m]: row(out-dim)=ob*16+quad*4+r, col(node)=l15+16m.
    {
      const int NT = has2 ? 64 : 32;
      int done = 0;
      while (done < NT) {                          // wave-uniform loop
        const int sel = done >> 4;                 // which 16-col group
        int srcv = (sel & 2) ? ((sel & 1) ? id3 : id2)
                             : ((sel & 1) ? id1 : id0);
        const int g = __builtin_amdgcn_readlane(srcv, done & 15);
        const bool m0 = (id0 == g), m1 = (id1 == g), m2 = (id2 == g), m3 = (id3 == g);
        float red[4][4];
        #pragma unroll
        for (int ob = 0; ob < 4; ++ob)
          #pragma unroll
          for (int r = 0; r < 4; ++r)
            red[ob][r] = (m0 ? acc3[ob][0][r] : 0.f) + (m1 ? acc3[ob][1][r] : 0.f)
                       + (m2 ? acc3[ob][2][r] : 0.f) + (m3 ? acc3[ob][3][r] : 0.f);
        #pragma unroll
        for (int s = 1; s <= 8; s <<= 1)
          #pragma unroll
          for (int ob = 0; ob < 4; ++ob)
            #pragma unroll
            for (int r = 0; r < 4; ++r)
              red[ob][r] += __shfl_xor(red[ob][r], s, 64);
        const int cnt = (int)((__popcll(__ballot(m0)) + __popcll(__ballot(m1)) +
                               __popcll(__ballot(m2)) + __popcll(__ballot(m3))) >> 2);
        if (l15 == 0) {                            // 4 lanes (one per quad) fire atomics
          #pragma unroll
          for (int ob = 0; ob < 4; ++ob)
            #pragma unroll
            for (int r = 0; r < 4; ++r)
              atomicAdd(&gsum[g * OUTD + ob * 16 + quad * 4 + r], red[ob][r]);
        }
        if (lane == 0) atomicAdd(&gcnt[g], cnt);
        done += cnt;                               // cnt >= 1: column `done` matches g
      }
    }
  }
}

extern "C" __global__ void gnn_finalize(const float* __restrict__ gsum,
                                        const int* __restrict__ gcnt,
                                        const float* __restrict__ b3,
                                        float* __restrict__ out)
{
  int i = blockIdx.x * 256 + threadIdx.x;
  if (i < N_GRAPHS * OUTD) {
    int g = i >> 6, o = i & 63;
    int c = gcnt[g];
    out[i] = (c > 0) ? (gsum[i] / (float)c + b3[o]) : 0.f;
  }
}

extern "C" void kernel_launch(void* const* d_in, const int* in_sizes, int n_in,
                              void* d_out, int out_size, void* d_ws, size_t ws_size,
                              hipStream_t stream) {
  const float* pos  = (const float*)d_in[0];
  const int*   z    = (const int*)d_in[1];
  const int*   batch= (const int*)d_in[2];
  const float* emb  = (const float*)d_in[3];
  const float* W1   = (const float*)d_in[4];
  const float* b1   = (const float*)d_in[5];
  const float* W2   = (const float*)d_in[6];
  const float* b2   = (const float*)d_in[7];
  const float* W3   = (const float*)d_in[8];
  const float* b3   = (const float*)d_in[9];

  float* gsum = (float*)d_ws;
  int*   gcnt = (int*)((char*)d_ws + WS_GCNT);
  unsigned short* Tg = (unsigned short*)((char*)d_ws + WS_T);

  // prep also zeroes gsum/gcnt (memset dispatch folded in)
  hipLaunchKernelGGL(gnn_prep, dim3(256), dim3(HID), 0, stream,
                     emb, W1, b1, Tg, (f32x4*)d_ws);

  hipFuncSetAttribute((const void*)gnn_main,
                      hipFuncAttributeMaxDynamicSharedMemorySize, LDS_BYTES);
  hipLaunchKernelGGL(gnn_main, dim3(NBLOCKS), dim3(512), LDS_BYTES, stream,
                     pos, z, batch, Tg, W1, W2, b2, W3, gsum, gcnt);
  hipLaunchKernelGGL(gnn_finalize, dim3((N_GRAPHS * OUTD + 255) / 256), dim3(256), 0, stream,
                     gsum, gcnt, b3, (float*)d_out);
}

// Round 16
// 130.910 us; speedup vs baseline: 1.5009x; 1.0119x over previous
//
#include <hip/hip_runtime.h>
#include <hip/hip_bf16.h>

#define N_NODES 500000
#define N_FEAT 125
#define HID 128
#define OUTD 64
#define N_GRAPHS 4096
#define N_TYPES 100
#define NPAIRS 7813   /* ceil(500000/64); pairs 0..7811 = 64 nodes, pair 7812 = 32 nodes */
#define NBLOCKS 256   /* 1 block/CU; occupancy reg-capped at 2 waves/SIMD (R2-R9) */
#define NWAVES 8
#define WPAD 136      /* bf16 row stride: 16B-aligned; 68 dwords == 4 mod 32 banks */

typedef float f32x4 __attribute__((ext_vector_type(4)));
typedef float f32x2 __attribute__((ext_vector_type(2)));
typedef short s16x8 __attribute__((ext_vector_type(8)));
typedef short s16x4 __attribute__((ext_vector_type(4)));

// LDS layout (bytes) — T + W2 + W3(K16 A-frags) + bias.  (w1 now in registers)
#define OFF_T 0
#define SZ_T (N_TYPES * WPAD * 2)                  // 27200
#define OFF_W2 (OFF_T + SZ_T)                      // 27200
#define OFF_W3K (OFF_W2 + HID * WPAD * 2)          // 62016 (4 ob x 8 oi x 64 lanes x 8B)
#define OFF_B2 (OFF_W3K + 4 * 8 * 64 * 8)          // 78400
#define LDS_BYTES (OFF_B2 + HID * 4)               // 78912

// ws layout (bytes)
#define WS_GSUM 0
#define WS_GCNT ((size_t)N_GRAPHS * OUTD * 4)      // 1048576
#define WS_T    (WS_GCNT + (size_t)N_GRAPHS * 4)   // 1064960
#define WS_ZERO WS_T                               // bytes zeroed (gsum+gcnt)
#define WS_ZERO_V4 (WS_ZERO / 16)                  // 66560 f32x4

__device__ __forceinline__ unsigned short f2bf(float f) {
  union { float f; unsigned u; } v; v.f = f;
  unsigned r = v.u + 0x7FFFu + ((v.u >> 16) & 1u);  // RNE
  return (unsigned short)(r >> 16);
}
__device__ __forceinline__ unsigned pk2bf(float a, float b) {
  __hip_bfloat162 h = __float22bfloat162_rn(float2{a, b});   // .x -> low 16, .y -> high 16
  union { __hip_bfloat162 h; unsigned u; } v; v.h = h;
  return v.u;
}
__device__ __forceinline__ s16x4 u2frag(uint2 v) {
  union { uint2 u; s16x4 s; } c; c.u = v; return c.s;
}

// ---- pre-pass: T[100][128] = emb @ W1[3:,:] + b1 (fp32 math, bf16 store) ----
extern "C" __global__ void gnn_prep(const float* __restrict__ emb,
                                    const float* __restrict__ W1,
                                    const float* __restrict__ b1,
                                    unsigned short* __restrict__ Tg,
                                    f32x4* __restrict__ wsz)
{
  const int j = threadIdx.x;                       // 256 blocks x 128 threads
  const int tid = blockIdx.x * 128 + j;
  for (int i = tid; i < WS_ZERO_V4; i += 256 * 128)
    wsz[i] = (f32x4){0.f, 0.f, 0.f, 0.f};
  const int g = blockIdx.x;
  if (g < N_TYPES) {
    float acc = b1[j];
    const float* er = emb + g * N_FEAT;
    for (int k = 0; k < N_FEAT; ++k)
      acc = fmaf(er[k], W1[(3 + k) * HID + j], acc);   // W1 read coalesced over j
    Tg[g * HID + j] = f2bf(acc);
  }
}

extern "C" __global__ void __launch_bounds__(512, 2)
gnn_main(const float* __restrict__ pos, const int* __restrict__ z,
         const int* __restrict__ batch, const unsigned short* __restrict__ Tg,
         const float* __restrict__ W1, const float* __restrict__ W2,
         const float* __restrict__ b2, const float* __restrict__ W3,
         float* __restrict__ gsum, int* __restrict__ gcnt)
{
  extern __shared__ char lds[];
  unsigned short* Tl  = (unsigned short*)(lds + OFF_T);
  unsigned short* w2t = (unsigned short*)(lds + OFF_W2);
  uint2* w3k = (uint2*)(lds + OFF_W3K);
  float* bias2 = (float*)(lds + OFF_B2);

  const int t = threadIdx.x;

  // ---- stage once per block ----
  for (int i = t; i < N_TYPES * HID; i += 512) {   // T: bf16, padded rows
    int g = i >> 7, f = i & 127;
    Tl[g * WPAD + f] = Tg[i];
  }
  for (int i = t; i < HID * HID; i += 512) {       // W2^T [n][k] bf16
    int k = i >> 7, n = i & 127;
    w2t[n * WPAD + k] = f2bf(W2[i]);
  }
  // W3 as per-lane K=16 A-fragments: idx = (ob*8+oi)*64 + lane.
  for (int i = t; i < 4 * 8 * 64; i += 512) {
    int ob = i >> 9, rest = i & 511;
    int oi = rest >> 6, ln = rest & 63;
    int q = ln >> 4, l = ln & 15;
    int f0 = oi * 16 + q * 4, o = ob * 16 + l;
    uint2 v;
    v.x = pk2bf(W3[(f0 + 0) * OUTD + o], W3[(f0 + 1) * OUTD + o]);
    v.y = pk2bf(W3[(f0 + 2) * OUTD + o], W3[(f0 + 3) * OUTD + o]);
    w3k[i] = v;
  }
  if (t < HID) bias2[t] = b2[t];

  const int wave = t >> 6, lane = t & 63, quad = lane >> 4, l15 = lane & 15;

  // ---- W1 pos-rows in REGISTERS as f32x2 pairs (96 VGPRs; budget is 256 at
  // (512,2) and we sat at 128 — R8's LDS eviction bought nothing).  Kills 24
  // ds_read_b128/pair of w1s re-reads on the ~40%-busy DS pipe. ----
  f32x2 w1r[3][4][4];
  #pragma unroll
  for (int c = 0; c < 3; ++c)
    #pragma unroll
    for (int k = 0; k < 4; ++k)
      #pragma unroll
      for (int j2 = 0; j2 < 4; ++j2)
        w1r[c][k][j2] = *(const f32x2*)(W1 + c * HID + k * 32 + quad * 8 + j2 * 2);

  __syncthreads();   // the ONLY block-wide barrier

  const int gwave = blockIdx.x * NWAVES + wave;

  // 64 nodes (2 tiles) per iteration (R10 skeleton, session-best 57.1us).
  // Layer-1 math in packed f32x2 (v_pk_fma_f32/v_pk_max_f32 dual-issue).
  for (int pair = gwave; pair < NPAIRS; pair += NBLOCKS * NWAVES) {
    const int base = pair * 64;
    const bool has2 = (pair != NPAIRS - 1);        // last pair: only 32 real nodes

    int id0 = batch[base + l15];
    int id1 = batch[base + 16 + l15];
    int id2 = -1, id3 = -1;
    if (has2) {
      id2 = batch[base + 32 + l15];
      id3 = batch[base + 48 + l15];
    }

    // ---- layer 1 in packed VALU, directly into MFMA B-fragments ----
    // h1[node][f] = relu(T[z][f] + px*W1r0[f] + py*W1r1[f] + pz*W1r2[f])
    s16x8 a[4][4];
    {
      f32x2 vx[4], vy[4], vz[4];
      const unsigned short* Tr[4];
      #pragma unroll
      for (int m = 0; m < 4; ++m) {
        int node = base + m * 16 + l15;
        node = node < N_NODES ? node : N_NODES - 1;   // clamp fake half of last pair
        const int zi = z[node];
        const float px = pos[node * 3], py = pos[node * 3 + 1], pz = pos[node * 3 + 2];
        vx[m] = (f32x2){px, px}; vy[m] = (f32x2){py, py}; vz[m] = (f32x2){pz, pz};
        Tr[m] = Tl + zi * WPAD;
      }
      #pragma unroll
      for (int k = 0; k < 4; ++k)
        #pragma unroll
        for (int m = 0; m < 4; ++m) {
          s16x8 tf = *(const s16x8*)(Tr[m] + k * 32 + quad * 8);
          s16x8 fr;
          #pragma unroll
          for (int j2 = 0; j2 < 4; ++j2) {
            const unsigned d = ((const unsigned*)&tf)[j2];
            f32x2 tv;
            ((unsigned*)&tv)[0] = d << 16;            // bf16 lo -> f32
            ((unsigned*)&tv)[1] = d & 0xffff0000u;    // bf16 hi -> f32
            f32x2 v = tv + vx[m] * w1r[0][k][j2]
                         + vy[m] * w1r[1][k][j2]
                         + vz[m] * w1r[2][k][j2];     // v_pk_fma_f32 x3
            v = __builtin_elementwise_max(v, (f32x2){0.f, 0.f});   // v_pk_max_f32
            ((unsigned*)&fr)[j2] = pk2bf(v[0], v[1]);
          }
          a[m][k] = fr;
        }
    }

    // ---- layer 2 + fused epilogue: the packed C-strip IS a K=16 B-fragment ----
    // b2 folded into the accumulator init (R12-verified; kills 64 adds/pair).
    uint2 pb[8][4];
    __builtin_amdgcn_s_setprio(1);
    #pragma unroll
    for (int oi = 0; oi < 8; ++oi) {
      f32x4 bv = *(const f32x4*)(bias2 + oi * 16 + quad * 4);
      f32x4 c[4] = {bv, bv, bv, bv};
      #pragma unroll
      for (int k = 0; k < 4; ++k) {
        s16x8 w = *(const s16x8*)(w2t + (oi * 16 + l15) * WPAD + k * 32 + quad * 8);
        #pragma unroll
        for (int m = 0; m < 4; ++m)
          c[m] = __builtin_amdgcn_mfma_f32_16x16x32_bf16(w, a[m][k], c[m], 0, 0, 0);
      }
      #pragma unroll
      for (int m = 0; m < 4; ++m) {
        pb[oi][m].x = pk2bf(fmaxf(c[m][0], 0.f), fmaxf(c[m][1], 0.f));
        pb[oi][m].y = pk2bf(fmaxf(c[m][2], 0.f), fmaxf(c[m][3], 0.f));
      }
    }
    __builtin_amdgcn_s_setprio(0);

    // ---- layer 3: mfma_f32_16x16x16_bf16, K-block = oi strip; wa feeds 4 MFMAs
    f32x4 acc3[4][4] = {};
    __builtin_amdgcn_s_setprio(1);
    #pragma unroll
    for (int ob = 0; ob < 4; ++ob)
      #pragma unroll
      for (int oi = 0; oi < 8; ++oi) {
        s16x4 wa = u2frag(w3k[(ob * 8 + oi) * 64 + lane]);
        #pragma unroll
        for (int m = 0; m < 4; ++m)
          acc3[ob][m] = __builtin_amdgcn_mfma_f32_16x16x16bf16_1k(
              wa, u2frag(pb[oi][m]), acc3[ob][m], 0, 0, 0);
      }
    __builtin_amdgcn_s_setprio(0);

    // ---- pool: in-register segmented reduce over up to 64 sorted columns ----
    // acc3[ob][m]: row(out-dim)=ob*16+quad*4+r, col(node)=l15+16m.
    {
      const int NT = has2 ? 64 : 32;
      int done = 0;
      while (done < NT) {                          // wave-uniform loop
        const int sel = done >> 4;                 // which 16-col group
        int srcv = (sel & 2) ? ((sel & 1) ? id3 : id2)
                             : ((sel & 1) ? id1 : id0);
        const int g = __builtin_amdgcn_readlane(srcv, done & 15);
        const bool m0 = (id0 == g), m1 = (id1 == g), m2 = (id2 == g), m3 = (id3 == g);
        float red[4][4];
        #pragma unroll
        for (int ob = 0; ob < 4; ++ob)
          #pragma unroll
          for (int r = 0; r < 4; ++r)
            red[ob][r] = (m0 ? acc3[ob][0][r] : 0.f) + (m1 ? acc3[ob][1][r] : 0.f)
                       + (m2 ? acc3[ob][2][r] : 0.f) + (m3 ? acc3[ob][3][r] : 0.f);
        #pragma unroll
        for (int s = 1; s <= 8; s <<= 1)
          #pragma unroll
          for (int ob = 0; ob < 4; ++ob)
            #pragma unroll
            for (int r = 0; r < 4; ++r)
              red[ob][r] += __shfl_xor(red[ob][r], s, 64);
        const int cnt = (int)((__popcll(__ballot(m0)) + __popcll(__ballot(m1)) +
                               __popcll(__ballot(m2)) + __popcll(__ballot(m3))) >> 2);
        if (l15 == 0) {                            // 4 lanes (one per quad) fire atomics
          #pragma unroll
          for (int ob = 0; ob < 4; ++ob)
            #pragma unroll
            for (int r = 0; r < 4; ++r)
              atomicAdd(&gsum[g * OUTD + ob * 16 + quad * 4 + r], red[ob][r]);
        }
        if (lane == 0) atomicAdd(&gcnt[g], cnt);
        done += cnt;                               // cnt >= 1: column `done` matches g
      }
    }
  }
}

extern "C" __global__ void gnn_finalize(const float* __restrict__ gsum,
                                        const int* __restrict__ gcnt,
                                        const float* __restrict__ b3,
                                        float* __restrict__ out)
{
  int i = blockIdx.x * 256 + threadIdx.x;
  if (i < N_GRAPHS * OUTD) {
    int g = i >> 6, o = i & 63;
    int c = gcnt[g];
    out[i] = (c > 0) ? (gsum[i] / (float)c + b3[o]) : 0.f;
  }
}

extern "C" void kernel_launch(void* const* d_in, const int* in_sizes, int n_in,
                              void* d_out, int out_size, void* d_ws, size_t ws_size,
                              hipStream_t stream) {
  const float* pos  = (const float*)d_in[0];
  const int*   z    = (const int*)d_in[1];
  const int*   batch= (const int*)d_in[2];
  const float* emb  = (const float*)d_in[3];
  const float* W1   = (const float*)d_in[4];
  const float* b1   = (const float*)d_in[5];
  const float* W2   = (const float*)d_in[6];
  const float* b2   = (const float*)d_in[7];
  const float* W3   = (const float*)d_in[8];
  const float* b3   = (const float*)d_in[9];

  float* gsum = (float*)d_ws;
  int*   gcnt = (int*)((char*)d_ws + WS_GCNT);
  unsigned short* Tg = (unsigned short*)((char*)d_ws + WS_T);

  // prep also zeroes gsum/gcnt (memset dispatch folded in)
  hipLaunchKernelGGL(gnn_prep, dim3(256), dim3(HID), 0, stream,
                     emb, W1, b1, Tg, (f32x4*)d_ws);

  hipFuncSetAttribute((const void*)gnn_main,
                      hipFuncAttributeMaxDynamicSharedMemorySize, LDS_BYTES);
  hipLaunchKernelGGL(gnn_main, dim3(NBLOCKS), dim3(512), LDS_BYTES, stream,
                     pos, z, batch, Tg, W1, W2, b2, W3, gsum, gcnt);
  hipLaunchKernelGGL(gnn_finalize, dim3((N_GRAPHS * OUTD + 255) / 256), dim3(256), 0, stream,
                     gsum, gcnt, b3, (float*)d_out);
}